// Round 10
// baseline (278.447 us; speedup 1.0000x reference)
//
#include <hip/hip_runtime.h>
#include <hip/hip_bf16.h>
#include <stdint.h>

// WTA dropout: per image keep values >= k-th largest (k = ceil(N*0.1)), zero rest.
// Round-10: replaced the exact full-histogram pass (33.5M LDS atomics ~27us)
// with sample->window + exact register count of key>=hi + radix select over
// ~65K window keys. Threshold known BEFORE mask pass -> no fixup kernel.
// 4 dispatches: sample+zero / count+collect / select / mask.

#define IMGS    32
#define NPER    1048576             // 2^20 elements per image
#define NPER4   (NPER / 4)          // 2^18 float4 per image
#define NBINS   8192                // 13-bit sample-hist bins
#define BPI     64                  // blocks per image, streaming kernels
#define MARGIN  32768u              // rank margin (26 sigma of sample error)
#define CAPC    98304               // per-image candidate capacity (~65K expected)
#define LCAP    2048                // per-block LDS candidate capacity (~1024 expected)
#define CSTRIDE 64                  // counters padded to 256 B apart

typedef float floatx4 __attribute__((ext_vector_type(4)));

__device__ __forceinline__ unsigned mapf(float f) {
    unsigned u = __float_as_uint(f);
    return (u & 0x80000000u) ? ~u : (u | 0x80000000u);   // monotonic float->uint
}

// Block-wide inclusive prefix sum over 256 values (one per thread), result in p[].
__device__ __forceinline__ void block_scan256(unsigned* p, int t, unsigned v) {
    p[t] = v;
    __syncthreads();
    #pragma unroll
    for (int off = 1; off < 256; off <<= 1) {
        unsigned u = (t >= off) ? p[t - off] : 0u;
        __syncthreads();
        p[t] += u;
        __syncthreads();
    }
}

// ---- K1: per-image 1/16 sample hist -> key window [lo,hi); zero counters ----
__global__ void k_sample(const float4* __restrict__ x4, uint2* __restrict__ win,
                         unsigned* __restrict__ cnt_hi, unsigned* __restrict__ candCnt,
                         unsigned k) {
    __shared__ unsigned h[NBINS];               // 32 KB
    __shared__ unsigned pre[256];
    __shared__ unsigned s_hi, s_lo;
    int t = threadIdx.x, img = blockIdx.x;
    if (t == 0) { cnt_hi[img * CSTRIDE] = 0u; candCnt[img * CSTRIDE] = 0u; }
    for (int j = t; j < NBINS; j += 256) h[j] = 0u;
    __syncthreads();

    long long ib = (long long)img * NPER4;
    // 64 chunks of 256 float4 (1024 elems), spread across the image: 65536 samples
    for (int c = 0; c < 64; ++c) {
        float4 v = x4[ib + (long long)c * 4096 + t];
        atomicAdd(&h[mapf(v.x) >> 19], 1u);
        atomicAdd(&h[mapf(v.y) >> 19], 1u);
        atomicAdd(&h[mapf(v.z) >> 19], 1u);
        atomicAdd(&h[mapf(v.w) >> 19], 1u);
    }
    __syncthreads();

    unsigned s = 0;
    #pragma unroll
    for (int j = 0; j < 32; ++j) s += h[t * 32 + ((j + t) & 31)];  // conflict-free
    block_scan256(pre, t, s);
    unsigned above = pre[255] - pre[t];         // sample mass in higher-key chunks

    unsigned tk_hi = (k > MARGIN) ? (k - MARGIN) : 1u;
    unsigned tk_lo = k + MARGIN;                // 137626 < NPER
    unsigned tgt_hi = (tk_hi + 15u) >> 4;       // ceil(target_rank / 16)
    unsigned tgt_lo = (tk_lo + 15u) >> 4;

    if (above < tgt_hi && above + s >= tgt_hi) {
        unsigned cum = above;
        for (int j = 31; j >= 0; --j) {
            unsigned v = h[t * 32 + j];
            cum += v;
            if (cum >= tgt_hi) { s_hi = (unsigned)(t * 32 + j); break; }
        }
    }
    if (above < tgt_lo && above + s >= tgt_lo) {
        unsigned cum = above;
        for (int j = 31; j >= 0; --j) {
            unsigned v = h[t * 32 + j];
            cum += v;
            if (cum >= tgt_lo) { s_lo = (unsigned)(t * 32 + j); break; }
        }
    }
    __syncthreads();
    if (t == 0) {
        unsigned hi_key = (s_hi >= 8191u) ? 0xFFFFFFFFu : ((s_hi + 1u) << 19);
        unsigned lo_key = s_lo << 19;
        win[img] = make_uint2(lo_key, hi_key);
    }
}

// ---- K2: exact count of key>=hi (registers) + collect window keys -----------
__global__ void k_count(const float4* __restrict__ x4, const uint2* __restrict__ win,
                        unsigned* __restrict__ cnt_hi, unsigned* __restrict__ candCnt,
                        unsigned* __restrict__ candKey) {
    __shared__ unsigned lkey[LCAP];             // 8 KB
    __shared__ unsigned red[256];
    __shared__ unsigned lcnt, gbase;
    int t = threadIdx.x, bx = blockIdx.x, img = bx >> 6;   // BPI = 64
    if (t == 0) lcnt = 0u;
    __syncthreads();

    uint2 w = win[img];                         // (lo_key, hi_key)
    unsigned c = 0;
    long long base4 = (long long)img * NPER4 + (long long)(bx & 63) * 4096;
    for (int it = 0; it < 16; ++it) {
        float4 v = x4[base4 + it * 256 + t];
        float* vp = &v.x;
        #pragma unroll
        for (int j = 0; j < 4; ++j) {
            unsigned key = mapf(vp[j]);
            c += (key >= w.y) ? 1u : 0u;
            if (key >= w.x && key < w.y) {
                unsigned p = atomicAdd(&lcnt, 1u);
                if (p < LCAP) lkey[p] = key;
            }
        }
    }
    red[t] = c;
    __syncthreads();
    for (int off = 128; off > 0; off >>= 1) {
        if (t < off) red[t] += red[t + off];
        __syncthreads();
    }
    unsigned n = lcnt;
    if (n > LCAP) n = LCAP;
    if (t == 0) {
        atomicAdd(&cnt_hi[img * CSTRIDE], red[0]);
        gbase = atomicAdd(&candCnt[img * CSTRIDE], n);
    }
    __syncthreads();
    unsigned gb = gbase;
    long long cb = (long long)img * CAPC;
    for (unsigned j = t; j < n; j += 256u) {
        unsigned pos = gb + j;
        if (pos < CAPC) candKey[cb + pos] = lkey[j];
    }
}

// ---- K3: 3-round MSB radix select (11+11+10 bits) -> exact threshold key ----
__global__ void k_select(const unsigned* __restrict__ cnt_hi,
                         const unsigned* __restrict__ candCnt,
                         const unsigned* __restrict__ candKey,
                         unsigned* __restrict__ thrArr, unsigned k) {
    int img = blockIdx.x, t = threadIdx.x;
    __shared__ unsigned h2[2048];               // 8 KB
    __shared__ unsigned pre[256];
    __shared__ unsigned sbin, srank;

    unsigned n = candCnt[img * CSTRIDE];
    if (n > CAPC) n = CAPC;
    unsigned chi = cnt_hi[img * CSTRIDE];
    unsigned r = (k > chi) ? (k - chi) : 1u;    // rank among window keys
    if (r > n) r = n;                           // safety clamp (never in practice)
    const unsigned* ck = candKey + (long long)img * CAPC;

    unsigned pfx = 0u;
    const int shifts[3]  = {21, 10, 0};
    const int fshift[3]  = {32, 21, 10};        // prefix-compare shift (32 = no filter)
    const int nbits[3]   = {11, 11, 10};
    for (int rd = 0; rd < 3; ++rd) {
        for (int j = t; j < 2048; j += 256) h2[j] = 0u;
        __syncthreads();
        int sh = shifts[rd];
        unsigned bmask = (1u << nbits[rd]) - 1u;
        for (unsigned j = t; j < n; j += 256u) {
            unsigned key = ck[j];               // L2-hot after round 0
            bool ok = (rd == 0) || ((key >> fshift[rd]) == pfx);
            if (ok) atomicAdd(&h2[(key >> sh) & bmask], 1u);
        }
        __syncthreads();

        int bpt = (int)((bmask + 1u) >> 8);     // bins per thread: 8,8,4
        unsigned s = 0;
        for (int j = 0; j < bpt; ++j) s += h2[t * bpt + ((j + t) & (bpt - 1))];
        block_scan256(pre, t, s);
        unsigned above = pre[255] - pre[t];
        if (above < r && above + s >= r) {
            unsigned cum = above;
            for (int j = bpt - 1; j >= 0; --j) {
                unsigned v = h2[t * bpt + j];
                cum += v;
                if (cum >= r) {
                    sbin = (unsigned)(t * bpt + j);
                    srank = r - (cum - v);
                    break;
                }
            }
        }
        __syncthreads();
        pfx = (pfx << nbits[rd]) | sbin;
        r = srank;
        __syncthreads();
    }
    if (t == 0) thrArr[img] = pfx;              // exact key of k-th largest
}

// ---- K4: pure streaming mask with the exact threshold -----------------------
__global__ void k_mask(const float4* __restrict__ x4, float4* __restrict__ o4,
                       const unsigned* __restrict__ thrArr) {
    int bx = blockIdx.x, t = threadIdx.x, img = bx >> 6;   // BPI = 64
    unsigned thr = thrArr[img];
    long long base4 = (long long)img * NPER4 + (long long)(bx & 63) * 4096;
    for (int it = 0; it < 16; ++it) {
        long long i = base4 + it * 256 + t;
        float4 v = x4[i];
        float4 o;
        o.x = (mapf(v.x) >= thr) ? v.x : 0.0f;
        o.y = (mapf(v.y) >= thr) ? v.y : 0.0f;
        o.z = (mapf(v.z) >= thr) ? v.z : 0.0f;
        o.w = (mapf(v.w) >= thr) ? v.w : 0.0f;
        floatx4 ov = { o.x, o.y, o.z, o.w };    // write-once stream: bypass L2
        __builtin_nontemporal_store(ov, (floatx4*)&o4[i]);
    }
}

extern "C" void kernel_launch(void* const* d_in, const int* in_sizes, int n_in,
                              void* d_out, int out_size, void* d_ws, size_t ws_size,
                              hipStream_t stream) {
    const float* x = (const float*)d_in[0];
    float* out = (float*)d_out;
    unsigned k = (unsigned)((NPER + 9) / 10);         // ceil(N*0.1) = 104858

    // workspace layout (~12.05 MB total)
    char* ws = (char*)d_ws;
    size_t padB = (size_t)IMGS * CSTRIDE * 4;         // 8 KB each
    unsigned* cnt_hi  = (unsigned*)ws;
    unsigned* candCnt = (unsigned*)(ws + padB);
    uint2*    win     = (uint2*)   (ws + 2 * padB);   // 256 B
    unsigned* thrArr  = (unsigned*)(ws + 2 * padB + 1024);
    unsigned* candKey = (unsigned*)(ws + 2 * padB + 2048);   // 12 MB

    dim3 blk(256);
    k_sample<<<dim3(IMGS), blk, 0, stream>>>((const float4*)x, win, cnt_hi, candCnt, k);
    k_count<<<dim3(IMGS * BPI), blk, 0, stream>>>((const float4*)x, win,
                                                  cnt_hi, candCnt, candKey);
    k_select<<<dim3(IMGS), blk, 0, stream>>>(cnt_hi, candCnt, candKey, thrArr, k);
    k_mask<<<dim3(IMGS * BPI), blk, 0, stream>>>((const float4*)x, (float4*)out, thrArr);
}

// Round 11
// 275.565 us; speedup vs baseline: 1.0105x; 1.0105x over previous
//
#include <hip/hip_runtime.h>
#include <hip/hip_bf16.h>
#include <stdint.h>

// WTA dropout: per image keep values >= k-th largest (k = ceil(N*0.1)), zero rest.
// Round-11: fix k_select's same-address LDS atomic storm (all window keys share
// top bits -> histogram of key>>21 hit ONE bin, 1.5M bank conflicts, 191us).
// Radix-select now runs on delta = key - window_lo (< 2^23 by window clamp):
// rounds on delta>>12 / (delta>>4)&0xFF / delta&0xF all spread across bins.

#define IMGS    32
#define NPER    1048576             // 2^20 elements per image
#define NPER4   (NPER / 4)          // 2^18 float4 per image
#define NBINS   8192                // 13-bit sample-hist bins
#define BPI     64                  // blocks per image, streaming kernels
#define MARGIN  32768u              // rank margin (26 sigma of sample error)
#define CAPC    98304               // per-image candidate capacity (~65K expected)
#define LCAP    2048                // per-block LDS candidate capacity (~1024 expected)
#define CSTRIDE 64                  // counters padded to 256 B apart

typedef float floatx4 __attribute__((ext_vector_type(4)));

__device__ __forceinline__ unsigned mapf(float f) {
    unsigned u = __float_as_uint(f);
    return (u & 0x80000000u) ? ~u : (u | 0x80000000u);   // monotonic float->uint
}

// Block-wide inclusive prefix sum over 256 values (one per thread), result in p[].
__device__ __forceinline__ void block_scan256(unsigned* p, int t, unsigned v) {
    p[t] = v;
    __syncthreads();
    #pragma unroll
    for (int off = 1; off < 256; off <<= 1) {
        unsigned u = (t >= off) ? p[t - off] : 0u;
        __syncthreads();
        p[t] += u;
        __syncthreads();
    }
}

// ---- K1: per-image 1/16 sample hist -> key window [lo,hi); zero counters ----
__global__ void k_sample(const float4* __restrict__ x4, uint2* __restrict__ win,
                         unsigned* __restrict__ cnt_hi, unsigned* __restrict__ candCnt,
                         unsigned k) {
    __shared__ unsigned h[NBINS];               // 32 KB
    __shared__ unsigned pre[256];
    __shared__ unsigned s_hi, s_lo;
    int t = threadIdx.x, img = blockIdx.x;
    if (t == 0) { cnt_hi[img * CSTRIDE] = 0u; candCnt[img * CSTRIDE] = 0u; }
    for (int j = t; j < NBINS; j += 256) h[j] = 0u;
    __syncthreads();

    long long ib = (long long)img * NPER4;
    // 64 chunks of 256 float4 (1024 elems), spread across the image: 65536 samples
    for (int c = 0; c < 64; ++c) {
        float4 v = x4[ib + (long long)c * 4096 + t];
        atomicAdd(&h[mapf(v.x) >> 19], 1u);
        atomicAdd(&h[mapf(v.y) >> 19], 1u);
        atomicAdd(&h[mapf(v.z) >> 19], 1u);
        atomicAdd(&h[mapf(v.w) >> 19], 1u);
    }
    __syncthreads();

    unsigned s = 0;
    #pragma unroll
    for (int j = 0; j < 32; ++j) s += h[t * 32 + ((j + t) & 31)];  // conflict-free
    block_scan256(pre, t, s);
    unsigned above = pre[255] - pre[t];         // sample mass in higher-key chunks

    unsigned tk_hi = (k > MARGIN) ? (k - MARGIN) : 1u;
    unsigned tk_lo = k + MARGIN;                // 137626 < NPER
    unsigned tgt_hi = (tk_hi + 15u) >> 4;       // ceil(target_rank / 16)
    unsigned tgt_lo = (tk_lo + 15u) >> 4;

    if (above < tgt_hi && above + s >= tgt_hi) {
        unsigned cum = above;
        for (int j = 31; j >= 0; --j) {
            unsigned v = h[t * 32 + j];
            cum += v;
            if (cum >= tgt_hi) { s_hi = (unsigned)(t * 32 + j); break; }
        }
    }
    if (above < tgt_lo && above + s >= tgt_lo) {
        unsigned cum = above;
        for (int j = 31; j >= 0; --j) {
            unsigned v = h[t * 32 + j];
            cum += v;
            if (cum >= tgt_lo) { s_lo = (unsigned)(t * 32 + j); break; }
        }
    }
    __syncthreads();
    if (t == 0) {
        unsigned shi = s_hi, slo = s_lo;
        if (shi - slo > 15u) slo = shi - 15u;   // window <= 16 bins -> delta < 2^23
        unsigned hi_key = (shi >= 8191u) ? 0xFFFFFFFFu : ((shi + 1u) << 19);
        unsigned lo_key = slo << 19;
        win[img] = make_uint2(lo_key, hi_key);
    }
}

// ---- K2: exact count of key>=hi (registers) + collect window keys -----------
__global__ void k_count(const float4* __restrict__ x4, const uint2* __restrict__ win,
                        unsigned* __restrict__ cnt_hi, unsigned* __restrict__ candCnt,
                        unsigned* __restrict__ candKey) {
    __shared__ unsigned lkey[LCAP];             // 8 KB
    __shared__ unsigned red[256];
    __shared__ unsigned lcnt, gbase;
    int t = threadIdx.x, bx = blockIdx.x, img = bx >> 6;   // BPI = 64
    if (t == 0) lcnt = 0u;
    __syncthreads();

    uint2 w = win[img];                         // (lo_key, hi_key)
    unsigned c = 0;
    long long base4 = (long long)img * NPER4 + (long long)(bx & 63) * 4096;
    for (int it = 0; it < 16; ++it) {
        float4 v = x4[base4 + it * 256 + t];
        float* vp = &v.x;
        #pragma unroll
        for (int j = 0; j < 4; ++j) {
            unsigned key = mapf(vp[j]);
            c += (key >= w.y) ? 1u : 0u;
            if (key >= w.x && key < w.y) {
                unsigned p = atomicAdd(&lcnt, 1u);
                if (p < LCAP) lkey[p] = key;
            }
        }
    }
    red[t] = c;
    __syncthreads();
    for (int off = 128; off > 0; off >>= 1) {
        if (t < off) red[t] += red[t + off];
        __syncthreads();
    }
    unsigned n = lcnt;
    if (n > LCAP) n = LCAP;
    if (t == 0) {
        atomicAdd(&cnt_hi[img * CSTRIDE], red[0]);
        gbase = atomicAdd(&candCnt[img * CSTRIDE], n);
    }
    __syncthreads();
    unsigned gb = gbase;
    long long cb = (long long)img * CAPC;
    for (unsigned j = t; j < n; j += 256u) {
        unsigned pos = gb + j;
        if (pos < CAPC) candKey[cb + pos] = lkey[j];
    }
}

// ---- K3: 3-round radix select on delta = key - lo (11+8+4 bits) -------------
__global__ void k_select(const uint2* __restrict__ win,
                         const unsigned* __restrict__ cnt_hi,
                         const unsigned* __restrict__ candCnt,
                         const unsigned* __restrict__ candKey,
                         unsigned* __restrict__ thrArr, unsigned k) {
    int img = blockIdx.x, t = threadIdx.x;
    __shared__ unsigned h2[2048];               // 8 KB
    __shared__ unsigned pre[256];
    __shared__ unsigned sbin, srank;

    unsigned n = candCnt[img * CSTRIDE];
    if (n > CAPC) n = CAPC;
    unsigned chi = cnt_hi[img * CSTRIDE];
    unsigned r = (k > chi) ? (k - chi) : 1u;    // rank among window keys
    if (r > n) r = n;                           // safety clamp (never in practice)
    unsigned lo = win[img].x;
    const unsigned* ck = candKey + (long long)img * CAPC;

    // rounds: bits of delta -- [22:12] 2048 bins / [11:4] 256 bins / [3:0] 16 bins
    const int shifts[3] = {12, 4, 0};
    const int fshift[3] = {32, 12, 4};          // filter shift (32 = no filter)
    const int binsA[3]  = {2048, 256, 16};
    unsigned pfx = 0u;
    for (int rd = 0; rd < 3; ++rd) {
        int bins = binsA[rd];
        for (int j = t; j < bins; j += 256) h2[j] = 0u;
        __syncthreads();
        int sh = shifts[rd], fs = fshift[rd];
        unsigned bmask = (unsigned)bins - 1u;
        #pragma unroll 4
        for (unsigned j = t; j < n; j += 256u) {
            unsigned delta = ck[j] - lo;        // < 2^23 (window clamp)
            bool ok = (rd == 0) || ((delta >> fs) == pfx);
            if (ok) atomicAdd(&h2[(delta >> sh) & bmask], 1u);
        }
        __syncthreads();

        int bpt = bins >> 8; if (bpt < 1) bpt = 1;   // bins per thread: 8,1,1
        unsigned s = 0;
        if (t * bpt < bins)
            for (int j = 0; j < bpt; ++j) s += h2[t * bpt + j];
        block_scan256(pre, t, s);
        unsigned above = pre[255] - pre[t];
        if (above < r && above + s >= r) {
            unsigned cum = above;
            for (int j = bpt - 1; j >= 0; --j) {
                unsigned v = h2[t * bpt + j];
                cum += v;
                if (cum >= r) {
                    sbin = (unsigned)(t * bpt + j);
                    srank = r - (cum - v);
                    break;
                }
            }
        }
        __syncthreads();
        pfx = (pfx << (rd == 0 ? 11 : (rd == 1 ? 8 : 4)));
        // rebuild prefix in delta-bit space: after rd0 pfx=bin(11b of [22:12]);
        // after rd1 pfx=(prev<<8)|bin = delta>>4; after rd2 full delta.
        pfx |= sbin;
        r = srank;
        __syncthreads();
    }
    if (t == 0) thrArr[img] = lo + pfx;         // exact key of k-th largest
}

// ---- K4: pure streaming mask with the exact threshold -----------------------
__global__ void k_mask(const float4* __restrict__ x4, float4* __restrict__ o4,
                       const unsigned* __restrict__ thrArr) {
    int bx = blockIdx.x, t = threadIdx.x, img = bx >> 6;   // BPI = 64
    unsigned thr = thrArr[img];
    long long base4 = (long long)img * NPER4 + (long long)(bx & 63) * 4096;
    for (int it = 0; it < 16; ++it) {
        long long i = base4 + it * 256 + t;
        float4 v = x4[i];
        float4 o;
        o.x = (mapf(v.x) >= thr) ? v.x : 0.0f;
        o.y = (mapf(v.y) >= thr) ? v.y : 0.0f;
        o.z = (mapf(v.z) >= thr) ? v.z : 0.0f;
        o.w = (mapf(v.w) >= thr) ? v.w : 0.0f;
        floatx4 ov = { o.x, o.y, o.z, o.w };    // write-once stream: bypass L2
        __builtin_nontemporal_store(ov, (floatx4*)&o4[i]);
    }
}

extern "C" void kernel_launch(void* const* d_in, const int* in_sizes, int n_in,
                              void* d_out, int out_size, void* d_ws, size_t ws_size,
                              hipStream_t stream) {
    const float* x = (const float*)d_in[0];
    float* out = (float*)d_out;
    unsigned k = (unsigned)((NPER + 9) / 10);         // ceil(N*0.1) = 104858

    // workspace layout (~12.05 MB total)
    char* ws = (char*)d_ws;
    size_t padB = (size_t)IMGS * CSTRIDE * 4;         // 8 KB each
    unsigned* cnt_hi  = (unsigned*)ws;
    unsigned* candCnt = (unsigned*)(ws + padB);
    uint2*    win     = (uint2*)   (ws + 2 * padB);   // 256 B
    unsigned* thrArr  = (unsigned*)(ws + 2 * padB + 1024);
    unsigned* candKey = (unsigned*)(ws + 2 * padB + 2048);   // 12 MB

    dim3 blk(256);
    k_sample<<<dim3(IMGS), blk, 0, stream>>>((const float4*)x, win, cnt_hi, candCnt, k);
    k_count<<<dim3(IMGS * BPI), blk, 0, stream>>>((const float4*)x, win,
                                                  cnt_hi, candCnt, candKey);
    k_select<<<dim3(IMGS), blk, 0, stream>>>(win, cnt_hi, candCnt, candKey, thrArr, k);
    k_mask<<<dim3(IMGS * BPI), blk, 0, stream>>>((const float4*)x, (float4*)out, thrArr);
}

// Round 12
// 129.582 us; speedup vs baseline: 2.1488x; 2.1266x over previous
//
#include <hip/hip_runtime.h>
#include <hip/hip_bf16.h>
#include <stdint.h>

// WTA dropout: per image keep values >= k-th largest (k = ceil(N*0.1)), zero rest.
// Round-12: k_select was latency-bound (32 blocks x scalar 4B loads x 3 passes
// over 65K keys = 186us at 1.2% occupancy). Fixes: MARGIN 32768->8192 (still
// 6.9 sigma of the 1/16-sample rank error) cuts candidates ~4x, and uint4
// candidate reads (4 keys/thread/iter) give ~10x fewer, pipelineable loop trips.

#define IMGS    32
#define NPER    1048576             // 2^20 elements per image
#define NPER4   (NPER / 4)          // 2^18 float4 per image
#define NBINS   8192                // 13-bit sample-hist bins
#define BPI     64                  // blocks per image, streaming kernels
#define MARGIN  8192u               // rank margin (6.9 sigma of sample error)
#define CAPC    98304               // per-image candidate capacity (~39K worst expected)
#define LCAP    2048                // per-block LDS candidate capacity (~620 expected)
#define CSTRIDE 64                  // counters padded to 256 B apart

typedef float floatx4 __attribute__((ext_vector_type(4)));

__device__ __forceinline__ unsigned mapf(float f) {
    unsigned u = __float_as_uint(f);
    return (u & 0x80000000u) ? ~u : (u | 0x80000000u);   // monotonic float->uint
}

// Block-wide inclusive prefix sum over 256 values (one per thread), result in p[].
__device__ __forceinline__ void block_scan256(unsigned* p, int t, unsigned v) {
    p[t] = v;
    __syncthreads();
    #pragma unroll
    for (int off = 1; off < 256; off <<= 1) {
        unsigned u = (t >= off) ? p[t - off] : 0u;
        __syncthreads();
        p[t] += u;
        __syncthreads();
    }
}

// ---- K1: per-image 1/16 sample hist -> key window [lo,hi); zero counters ----
__global__ void k_sample(const float4* __restrict__ x4, uint2* __restrict__ win,
                         unsigned* __restrict__ cnt_hi, unsigned* __restrict__ candCnt,
                         unsigned k) {
    __shared__ unsigned h[NBINS];               // 32 KB
    __shared__ unsigned pre[256];
    __shared__ unsigned s_hi, s_lo;
    int t = threadIdx.x, img = blockIdx.x;
    if (t == 0) { cnt_hi[img * CSTRIDE] = 0u; candCnt[img * CSTRIDE] = 0u; }
    for (int j = t; j < NBINS; j += 256) h[j] = 0u;
    __syncthreads();

    long long ib = (long long)img * NPER4;
    // 64 chunks of 256 float4 (1024 elems), spread across the image: 65536 samples
    for (int c = 0; c < 64; ++c) {
        float4 v = x4[ib + (long long)c * 4096 + t];
        atomicAdd(&h[mapf(v.x) >> 19], 1u);
        atomicAdd(&h[mapf(v.y) >> 19], 1u);
        atomicAdd(&h[mapf(v.z) >> 19], 1u);
        atomicAdd(&h[mapf(v.w) >> 19], 1u);
    }
    __syncthreads();

    unsigned s = 0;
    #pragma unroll
    for (int j = 0; j < 32; ++j) s += h[t * 32 + ((j + t) & 31)];  // conflict-free
    block_scan256(pre, t, s);
    unsigned above = pre[255] - pre[t];         // sample mass in higher-key chunks

    unsigned tk_hi = (k > MARGIN) ? (k - MARGIN) : 1u;
    unsigned tk_lo = k + MARGIN;
    unsigned tgt_hi = (tk_hi + 15u) >> 4;       // ceil(target_rank / 16)
    unsigned tgt_lo = (tk_lo + 15u) >> 4;

    if (above < tgt_hi && above + s >= tgt_hi) {
        unsigned cum = above;
        for (int j = 31; j >= 0; --j) {
            unsigned v = h[t * 32 + j];
            cum += v;
            if (cum >= tgt_hi) { s_hi = (unsigned)(t * 32 + j); break; }
        }
    }
    if (above < tgt_lo && above + s >= tgt_lo) {
        unsigned cum = above;
        for (int j = 31; j >= 0; --j) {
            unsigned v = h[t * 32 + j];
            cum += v;
            if (cum >= tgt_lo) { s_lo = (unsigned)(t * 32 + j); break; }
        }
    }
    __syncthreads();
    if (t == 0) {
        unsigned shi = s_hi, slo = s_lo;
        if (shi - slo > 15u) slo = shi - 15u;   // window <= 16 bins -> delta < 2^23
        unsigned hi_key = (shi >= 8191u) ? 0xFFFFFFFFu : ((shi + 1u) << 19);
        unsigned lo_key = slo << 19;
        win[img] = make_uint2(lo_key, hi_key);
    }
}

// ---- K2: exact count of key>=hi (registers) + collect window keys -----------
__global__ void k_count(const float4* __restrict__ x4, const uint2* __restrict__ win,
                        unsigned* __restrict__ cnt_hi, unsigned* __restrict__ candCnt,
                        unsigned* __restrict__ candKey) {
    __shared__ unsigned lkey[LCAP];             // 8 KB
    __shared__ unsigned red[256];
    __shared__ unsigned lcnt, gbase;
    int t = threadIdx.x, bx = blockIdx.x, img = bx >> 6;   // BPI = 64
    if (t == 0) lcnt = 0u;
    __syncthreads();

    uint2 w = win[img];                         // (lo_key, hi_key)
    unsigned c = 0;
    long long base4 = (long long)img * NPER4 + (long long)(bx & 63) * 4096;
    for (int it = 0; it < 16; ++it) {
        float4 v = x4[base4 + it * 256 + t];
        float* vp = &v.x;
        #pragma unroll
        for (int j = 0; j < 4; ++j) {
            unsigned key = mapf(vp[j]);
            c += (key >= w.y) ? 1u : 0u;
            if (key >= w.x && key < w.y) {
                unsigned p = atomicAdd(&lcnt, 1u);
                if (p < LCAP) lkey[p] = key;
            }
        }
    }
    red[t] = c;
    __syncthreads();
    for (int off = 128; off > 0; off >>= 1) {
        if (t < off) red[t] += red[t + off];
        __syncthreads();
    }
    unsigned n = lcnt;
    if (n > LCAP) n = LCAP;
    if (t == 0) {
        atomicAdd(&cnt_hi[img * CSTRIDE], red[0]);
        gbase = atomicAdd(&candCnt[img * CSTRIDE], n);
    }
    __syncthreads();
    unsigned gb = gbase;
    long long cb = (long long)img * CAPC;
    for (unsigned j = t; j < n; j += 256u) {
        unsigned pos = gb + j;
        if (pos < CAPC) candKey[cb + pos] = lkey[j];
    }
}

// ---- K3: 3-round radix select on delta = key - lo (11+8+4 bits), uint4 reads
__global__ void k_select(const uint2* __restrict__ win,
                         const unsigned* __restrict__ cnt_hi,
                         const unsigned* __restrict__ candCnt,
                         const unsigned* __restrict__ candKey,
                         unsigned* __restrict__ thrArr, unsigned k) {
    int img = blockIdx.x, t = threadIdx.x;
    __shared__ unsigned h2[2048];               // 8 KB
    __shared__ unsigned pre[256];
    __shared__ unsigned sbin, srank;

    unsigned n = candCnt[img * CSTRIDE];
    if (n > CAPC) n = CAPC;
    unsigned chi = cnt_hi[img * CSTRIDE];
    unsigned r = (k > chi) ? (k - chi) : 1u;    // rank among window keys
    if (r > n) r = n;                           // safety clamp (never in practice)
    unsigned lo = win[img].x;
    const uint4* ck4 = (const uint4*)(candKey + (long long)img * CAPC);
    unsigned n4 = (n + 3u) >> 2;

    // rounds: bits of delta -- [22:12] 2048 bins / [11:4] 256 bins / [3:0] 16 bins
    const int shifts[3] = {12, 4, 0};
    const int fshift[3] = {31, 12, 4};          // filter shift (rd0: no filter)
    const int binsA[3]  = {2048, 256, 16};
    unsigned pfx = 0u;
    for (int rd = 0; rd < 3; ++rd) {
        int bins = binsA[rd];
        for (int j = t; j < bins; j += 256) h2[j] = 0u;
        __syncthreads();
        int sh = shifts[rd], fs = fshift[rd];
        unsigned bmask = (unsigned)bins - 1u;
        bool nofilt = (rd == 0);
        #pragma unroll 2
        for (unsigned j = t; j < n4; j += 256u) {
            uint4 kk = ck4[j];                  // 16B coalesced, pipelineable
            unsigned base = j * 4u;
            unsigned kw[4] = {kk.x, kk.y, kk.z, kk.w};
            #pragma unroll
            for (int c = 0; c < 4; ++c) {
                if (base + (unsigned)c < n) {
                    unsigned delta = kw[c] - lo;        // < 2^23 (window clamp)
                    bool ok = nofilt || ((delta >> fs) == pfx);
                    if (ok) atomicAdd(&h2[(delta >> sh) & bmask], 1u);
                }
            }
        }
        __syncthreads();

        int bpt = bins >> 8; if (bpt < 1) bpt = 1;   // bins per thread: 8,1,1
        unsigned s = 0;
        if (t * bpt < bins)
            for (int j = 0; j < bpt; ++j) s += h2[t * bpt + j];
        block_scan256(pre, t, s);
        unsigned above = pre[255] - pre[t];
        if (above < r && above + s >= r) {
            unsigned cum = above;
            for (int j = bpt - 1; j >= 0; --j) {
                unsigned v = h2[t * bpt + j];
                cum += v;
                if (cum >= r) {
                    sbin = (unsigned)(t * bpt + j);
                    srank = r - (cum - v);
                    break;
                }
            }
        }
        __syncthreads();
        pfx = (pfx << (rd == 0 ? 11 : (rd == 1 ? 8 : 4))) | sbin;
        r = srank;
        __syncthreads();
    }
    if (t == 0) thrArr[img] = lo + pfx;         // exact key of k-th largest
}

// ---- K4: pure streaming mask with the exact threshold -----------------------
__global__ void k_mask(const float4* __restrict__ x4, float4* __restrict__ o4,
                       const unsigned* __restrict__ thrArr) {
    int bx = blockIdx.x, t = threadIdx.x, img = bx >> 6;   // BPI = 64
    unsigned thr = thrArr[img];
    long long base4 = (long long)img * NPER4 + (long long)(bx & 63) * 4096;
    for (int it = 0; it < 16; ++it) {
        long long i = base4 + it * 256 + t;
        float4 v = x4[i];
        float4 o;
        o.x = (mapf(v.x) >= thr) ? v.x : 0.0f;
        o.y = (mapf(v.y) >= thr) ? v.y : 0.0f;
        o.z = (mapf(v.z) >= thr) ? v.z : 0.0f;
        o.w = (mapf(v.w) >= thr) ? v.w : 0.0f;
        floatx4 ov = { o.x, o.y, o.z, o.w };    // write-once stream: bypass L2
        __builtin_nontemporal_store(ov, (floatx4*)&o4[i]);
    }
}

extern "C" void kernel_launch(void* const* d_in, const int* in_sizes, int n_in,
                              void* d_out, int out_size, void* d_ws, size_t ws_size,
                              hipStream_t stream) {
    const float* x = (const float*)d_in[0];
    float* out = (float*)d_out;
    unsigned k = (unsigned)((NPER + 9) / 10);         // ceil(N*0.1) = 104858

    // workspace layout (~12.05 MB total)
    char* ws = (char*)d_ws;
    size_t padB = (size_t)IMGS * CSTRIDE * 4;         // 8 KB each
    unsigned* cnt_hi  = (unsigned*)ws;
    unsigned* candCnt = (unsigned*)(ws + padB);
    uint2*    win     = (uint2*)   (ws + 2 * padB);   // 256 B
    unsigned* thrArr  = (unsigned*)(ws + 2 * padB + 1024);
    unsigned* candKey = (unsigned*)(ws + 2 * padB + 2048);   // 12 MB

    dim3 blk(256);
    k_sample<<<dim3(IMGS), blk, 0, stream>>>((const float4*)x, win, cnt_hi, candCnt, k);
    k_count<<<dim3(IMGS * BPI), blk, 0, stream>>>((const float4*)x, win,
                                                  cnt_hi, candCnt, candKey);
    k_select<<<dim3(IMGS), blk, 0, stream>>>(win, cnt_hi, candCnt, candKey, thrArr, k);
    k_mask<<<dim3(IMGS * BPI), blk, 0, stream>>>((const float4*)x, (float4*)out, thrArr);
}

// Round 13
// 118.498 us; speedup vs baseline: 2.3498x; 1.0935x over previous
//
#include <hip/hip_runtime.h>
#include <hip/hip_bf16.h>
#include <stdint.h>

// WTA dropout: per image keep values >= k-th largest (k = ceil(N*0.1)), zero rest.
// Round-13: ONE streaming pass over x. k_count+k_mask fused: count key>=hi in
// registers, collect in-window candidates via LDS staging, write provisional
// output (key>=lo ? x : 0) with nt stores. Tiny select -> exact thr; full-grid
// fixup zeroes candidates below thr. x read once (was twice).

#define IMGS    32
#define NPER    1048576             // 2^20 elements per image
#define NPER4   (NPER / 4)          // 2^18 float4 per image
#define NBINS   8192                // 13-bit sample-hist bins
#define BPI     64                  // blocks per image, streaming kernel
#define MARGIN  8192u               // rank margin (6.9 sigma of 1/16-sample error)
#define CAPC    98304               // per-image candidate capacity (~40K worst expected)
#define LCAP    2048                // per-block LDS candidate capacity (~620 expected)
#define CSTRIDE 64                  // counters padded to 256 B apart

typedef float floatx4 __attribute__((ext_vector_type(4)));

__device__ __forceinline__ unsigned mapf(float f) {
    unsigned u = __float_as_uint(f);
    return (u & 0x80000000u) ? ~u : (u | 0x80000000u);   // monotonic float->uint
}

// Block-wide inclusive prefix sum over 256 values (one per thread), result in p[].
__device__ __forceinline__ void block_scan256(unsigned* p, int t, unsigned v) {
    p[t] = v;
    __syncthreads();
    #pragma unroll
    for (int off = 1; off < 256; off <<= 1) {
        unsigned u = (t >= off) ? p[t - off] : 0u;
        __syncthreads();
        p[t] += u;
        __syncthreads();
    }
}

// ---- K1: per-image 1/16 sample hist -> key window [lo,hi); zero counters ----
__global__ void k_sample(const float4* __restrict__ x4, uint2* __restrict__ win,
                         unsigned* __restrict__ cnt_hi, unsigned* __restrict__ candCnt,
                         unsigned k) {
    __shared__ unsigned h[NBINS];               // 32 KB
    __shared__ unsigned pre[256];
    __shared__ unsigned s_hi, s_lo;
    int t = threadIdx.x, img = blockIdx.x;
    if (t == 0) { cnt_hi[img * CSTRIDE] = 0u; candCnt[img * CSTRIDE] = 0u; }
    for (int j = t; j < NBINS; j += 256) h[j] = 0u;
    __syncthreads();

    long long ib = (long long)img * NPER4;
    // 64 chunks of 256 float4 (1024 elems) spread across image: 65536 samples.
    // 4 independent loads per iter for memory-level parallelism.
    for (int c = 0; c < 16; ++c) {
        float4 a = x4[ib + (long long)(c      ) * 4096 + t];
        float4 b = x4[ib + (long long)(c + 16) * 4096 + t];
        float4 d = x4[ib + (long long)(c + 32) * 4096 + t];
        float4 e = x4[ib + (long long)(c + 48) * 4096 + t];
        atomicAdd(&h[mapf(a.x) >> 19], 1u); atomicAdd(&h[mapf(a.y) >> 19], 1u);
        atomicAdd(&h[mapf(a.z) >> 19], 1u); atomicAdd(&h[mapf(a.w) >> 19], 1u);
        atomicAdd(&h[mapf(b.x) >> 19], 1u); atomicAdd(&h[mapf(b.y) >> 19], 1u);
        atomicAdd(&h[mapf(b.z) >> 19], 1u); atomicAdd(&h[mapf(b.w) >> 19], 1u);
        atomicAdd(&h[mapf(d.x) >> 19], 1u); atomicAdd(&h[mapf(d.y) >> 19], 1u);
        atomicAdd(&h[mapf(d.z) >> 19], 1u); atomicAdd(&h[mapf(d.w) >> 19], 1u);
        atomicAdd(&h[mapf(e.x) >> 19], 1u); atomicAdd(&h[mapf(e.y) >> 19], 1u);
        atomicAdd(&h[mapf(e.z) >> 19], 1u); atomicAdd(&h[mapf(e.w) >> 19], 1u);
    }
    __syncthreads();

    unsigned s = 0;
    #pragma unroll
    for (int j = 0; j < 32; ++j) s += h[t * 32 + ((j + t) & 31)];  // conflict-free
    block_scan256(pre, t, s);
    unsigned above = pre[255] - pre[t];         // sample mass in higher-key chunks

    unsigned tk_hi = (k > MARGIN) ? (k - MARGIN) : 1u;
    unsigned tk_lo = k + MARGIN;
    unsigned tgt_hi = (tk_hi + 15u) >> 4;       // ceil(target_rank / 16)
    unsigned tgt_lo = (tk_lo + 15u) >> 4;

    if (above < tgt_hi && above + s >= tgt_hi) {
        unsigned cum = above;
        for (int j = 31; j >= 0; --j) {
            unsigned v = h[t * 32 + j];
            cum += v;
            if (cum >= tgt_hi) { s_hi = (unsigned)(t * 32 + j); break; }
        }
    }
    if (above < tgt_lo && above + s >= tgt_lo) {
        unsigned cum = above;
        for (int j = 31; j >= 0; --j) {
            unsigned v = h[t * 32 + j];
            cum += v;
            if (cum >= tgt_lo) { s_lo = (unsigned)(t * 32 + j); break; }
        }
    }
    __syncthreads();
    if (t == 0) {
        unsigned shi = s_hi, slo = s_lo;
        if (shi - slo > 15u) slo = shi - 15u;   // window <= 16 bins -> delta < 2^23
        unsigned hi_key = (shi >= 8191u) ? 0xFFFFFFFFu : ((shi + 1u) << 19);
        unsigned lo_key = slo << 19;
        win[img] = make_uint2(lo_key, hi_key);
    }
}

// ---- K2: fused stream: count key>=hi + collect window cands + provisional mask
__global__ void k_count_mask(const float4* __restrict__ x4, float4* __restrict__ o4,
                             const uint2* __restrict__ win,
                             unsigned* __restrict__ cnt_hi, unsigned* __restrict__ candCnt,
                             unsigned* __restrict__ candKey, unsigned* __restrict__ candIdx) {
    __shared__ unsigned lkey[LCAP];             // 8 KB
    __shared__ unsigned lidx[LCAP];             // 8 KB
    __shared__ unsigned red[256];
    __shared__ unsigned lcnt, gbase;
    int t = threadIdx.x, bx = blockIdx.x, img = bx >> 6;   // BPI = 64
    if (t == 0) lcnt = 0u;
    __syncthreads();

    uint2 w = win[img];                         // (lo_key, hi_key)
    unsigned c = 0;
    long long base4 = (long long)img * NPER4 + (long long)(bx & 63) * 4096;
    for (int it = 0; it < 16; ++it) {
        long long i = base4 + it * 256 + t;
        float4 v = x4[i];
        unsigned ebase = (unsigned)(i & (NPER4 - 1)) * 4u;
        float4 o;
        float* vp = &v.x;
        float* op = &o.x;
        #pragma unroll
        for (int j = 0; j < 4; ++j) {
            float cv = vp[j];
            unsigned key = mapf(cv);
            c += (key >= w.y) ? 1u : 0u;
            op[j] = (key >= w.x) ? cv : 0.0f;    // provisional keep above lo
            if (key >= w.x && key < w.y) {       // in-window: candidate
                unsigned p = atomicAdd(&lcnt, 1u);
                if (p < LCAP) { lkey[p] = key; lidx[p] = ebase + (unsigned)j; }
            }
        }
        floatx4 ov = { o.x, o.y, o.z, o.w };    // write-once stream: bypass L2
        __builtin_nontemporal_store(ov, (floatx4*)&o4[i]);
    }
    red[t] = c;
    __syncthreads();
    for (int off = 128; off > 0; off >>= 1) {
        if (t < off) red[t] += red[t + off];
        __syncthreads();
    }
    unsigned n = lcnt;
    if (n > LCAP) n = LCAP;
    if (t == 0) {
        atomicAdd(&cnt_hi[img * CSTRIDE], red[0]);
        gbase = atomicAdd(&candCnt[img * CSTRIDE], n);
    }
    __syncthreads();
    unsigned gb = gbase;
    long long cb = (long long)img * CAPC;
    for (unsigned j = t; j < n; j += 256u) {
        unsigned pos = gb + j;
        if (pos < CAPC) {
            candKey[cb + pos] = lkey[j];
            candIdx[cb + pos] = lidx[j];
        }
    }
}

// ---- K3: 2-round radix select on delta = key - lo (11 + 12 bits) ------------
__global__ void k_select(const uint2* __restrict__ win,
                         const unsigned* __restrict__ cnt_hi,
                         const unsigned* __restrict__ candCnt,
                         const unsigned* __restrict__ candKey,
                         unsigned* __restrict__ thrArr, unsigned k) {
    int img = blockIdx.x, t = threadIdx.x;
    __shared__ unsigned h2[4096];               // 16 KB
    __shared__ unsigned pre[256];
    __shared__ unsigned sbin, srank;

    unsigned n = candCnt[img * CSTRIDE];
    if (n > CAPC) n = CAPC;
    unsigned chi = cnt_hi[img * CSTRIDE];
    unsigned r = (k > chi) ? (k - chi) : 1u;    // rank among window keys
    if (r > n) r = n;                           // safety clamp
    unsigned lo = win[img].x;
    const uint4* ck4 = (const uint4*)(candKey + (long long)img * CAPC);
    unsigned n4 = (n + 3u) >> 2;

    // rounds on delta (< 2^23): [22:12] 2048 bins, then [11:0] 4096 bins
    unsigned pfx = 0u;
    for (int rd = 0; rd < 2; ++rd) {
        int bins = rd == 0 ? 2048 : 4096;
        int sh = rd == 0 ? 12 : 0;
        for (int j = t; j < bins; j += 256) h2[j] = 0u;
        __syncthreads();
        unsigned bmask = (unsigned)bins - 1u;
        for (unsigned j = t; j < n4; j += 256u) {
            uint4 kk = ck4[j];                  // 16B coalesced, pipelineable
            unsigned base = j * 4u;
            unsigned kw[4] = {kk.x, kk.y, kk.z, kk.w};
            #pragma unroll
            for (int c2 = 0; c2 < 4; ++c2) {
                if (base + (unsigned)c2 < n) {
                    unsigned delta = kw[c2] - lo;        // < 2^23 (window clamp)
                    bool ok = (rd == 0) || ((delta >> 12) == pfx);
                    if (ok) atomicAdd(&h2[(delta >> sh) & bmask], 1u);
                }
            }
        }
        __syncthreads();

        int bpt = bins >> 8;                    // bins per thread: 8, 16
        unsigned s = 0;
        for (int j = 0; j < bpt; ++j) s += h2[t * bpt + ((j + t) & (bpt - 1))];
        block_scan256(pre, t, s);
        unsigned above = pre[255] - pre[t];
        if (above < r && above + s >= r) {
            unsigned cum = above;
            for (int j = bpt - 1; j >= 0; --j) {
                unsigned v = h2[t * bpt + j];
                cum += v;
                if (cum >= r) {
                    sbin = (unsigned)(t * bpt + j);
                    srank = r - (cum - v);
                    break;
                }
            }
        }
        __syncthreads();
        pfx = (rd == 0) ? sbin : ((pfx << 12) | sbin);
        r = srank;
        __syncthreads();
    }
    if (t == 0) thrArr[img] = lo + pfx;         // exact key of k-th largest
}

// ---- K4: full-grid fixup: zero candidates with key < thr --------------------
__global__ void k_fixup(float* __restrict__ out, const unsigned* __restrict__ thrArr,
                        const unsigned* __restrict__ candCnt,
                        const unsigned* __restrict__ candKey,
                        const unsigned* __restrict__ candIdx) {
    int bx = blockIdx.x, t = threadIdx.x, img = bx >> 6;   // BPI = 64
    unsigned n = candCnt[img * CSTRIDE];
    if (n > CAPC) n = CAPC;
    unsigned thr = thrArr[img];
    const unsigned* ck = candKey + (long long)img * CAPC;
    const unsigned* ci = candIdx + (long long)img * CAPC;
    float* oi = out + (long long)img * NPER;
    // slice (bx & 63) of this image's candidate list, coalesced
    for (unsigned j = (unsigned)(bx & 63) * 256u + t; j < n; j += 64u * 256u) {
        if (ck[j] < thr) oi[ci[j]] = 0.0f;
    }
}

extern "C" void kernel_launch(void* const* d_in, const int* in_sizes, int n_in,
                              void* d_out, int out_size, void* d_ws, size_t ws_size,
                              hipStream_t stream) {
    const float* x = (const float*)d_in[0];
    float* out = (float*)d_out;
    unsigned k = (unsigned)((NPER + 9) / 10);         // ceil(N*0.1) = 104858

    // workspace layout (~24 MB total)
    char* ws = (char*)d_ws;
    size_t padB = (size_t)IMGS * CSTRIDE * 4;         // 8 KB each
    unsigned* cnt_hi  = (unsigned*)ws;
    unsigned* candCnt = (unsigned*)(ws + padB);
    uint2*    win     = (uint2*)   (ws + 2 * padB);   // 256 B
    unsigned* thrArr  = (unsigned*)(ws + 2 * padB + 1024);
    unsigned* candKey = (unsigned*)(ws + 2 * padB + 2048);               // 12 MB
    unsigned* candIdx = (unsigned*)(ws + 2 * padB + 2048
                                       + (size_t)IMGS * CAPC * 4);       // 12 MB

    dim3 blk(256);
    k_sample<<<dim3(IMGS), blk, 0, stream>>>((const float4*)x, win, cnt_hi, candCnt, k);
    k_count_mask<<<dim3(IMGS * BPI), blk, 0, stream>>>((const float4*)x, (float4*)out,
                                                       win, cnt_hi, candCnt,
                                                       candKey, candIdx);
    k_select<<<dim3(IMGS), blk, 0, stream>>>(win, cnt_hi, candCnt, candKey, thrArr, k);
    k_fixup<<<dim3(IMGS * BPI), blk, 0, stream>>>(out, thrArr, candCnt, candKey, candIdx);
}